// Round 1
// 437.602 us; speedup vs baseline: 1.6503x; 1.6503x over previous
//
#include <hip/hip_runtime.h>
#include <math.h>

// Problem constants
#define B_ 16
#define C_ 64
#define H_ 128
#define W_ 128
#define HW_ (H_*W_)
#define OUT_ELEMS 16777216   // B*C*H*W

// Workspace byte offsets
#define CHM_B    0                      // 512 f32
#define PWA_B    2048                   // 16384 u16
#define AH_B     34816                  // 258048 u16
#define FEA_B(s) (550912u + (size_t)(s)*33554432u)  // 4 x 16777216 u16

// A-image u16 offsets within AH
#define A_S0   0
#define A_S(s) (36864 + ((s)-1)*73728)  // s = 1..3

typedef __attribute__((ext_vector_type(4))) short  v4s;
typedef __attribute__((ext_vector_type(8))) short  v8s;
typedef __attribute__((ext_vector_type(4))) float  v4f;

__device__ __forceinline__ ushort f2bf(float f) {
    unsigned u = __builtin_bit_cast(unsigned, f);
    unsigned r = u + 0x7FFFu + ((u >> 16) & 1u);
    return (ushort)(r >> 16);
}
__device__ __forceinline__ v8s ld_b64x2(const ushort* p) {  // 8B-aligned
    v4s a = *(const v4s*)(const void*)p;
    v4s b = *(const v4s*)(const void*)(p + 4);
    return __builtin_shufflevector(a, b, 0, 1, 2, 3, 4, 5, 6, 7);
}

// ---------------------------------------------------------------------------
__global__ __launch_bounds__(64) void mask_kernel(
    const float* __restrict__ gum, const float* __restrict__ par,
    float* __restrict__ chm, float* __restrict__ out_tail)
{
    int c = threadIdx.x;
    #pragma unroll
    for (int i = 0; i < 4; ++i) {
        int base = (c*4 + i)*2;
        float g0 = -logf(-logf(gum[base]));
        float g1 = -logf(-logf(gum[base+1]));
        float a0 = par[base] + g0, a1 = par[base+1] + g1;
        float mx = fmaxf(a0, a1);
        float e0 = expf(a0 - mx), e1 = expf(a1 - mx);
        float inv = 1.0f / (e0 + e1);
        float m0 = e0*inv, m1 = e1*inv;
        chm[base] = m0; chm[base+1] = m1;
        out_tail[base] = m0; out_tail[base+1] = m1;
    }
}

// ---------------------------------------------------------------------------
// Build bf16 A-images (gate-folded weights) + bf16 pw weights.
// Stage0:  AH[A_S0 + ((c*9+t)*64 + oc)*32 + icl]
// Stage s: AH[A_S(s) + ((c*9+t)*128 + ocM)*32 + icl], ocM = 2*oc + set
__global__ __launch_bounds__(256) void prep_kernel(
    const float* __restrict__ w0, const float* __restrict__ w1,
    const float* __restrict__ w2, const float* __restrict__ w3,
    const float* __restrict__ wc, const float* __restrict__ chm,
    ushort* __restrict__ AH, ushort* __restrict__ pwA)
{
    int idx = blockIdx.x*256 + threadIdx.x;   // < 274432
    if (idx < 36864) {
        int blk = idx >> 11;            // c*9+t, 0..17
        int r3  = idx & 2047;
        int oc = r3 >> 5, icl = r3 & 31;
        int cc = blk / 9, t = blk - 9*cc;
        int ic = cc*32 + icl;
        AH[idx] = f2bf(w0[(oc*64 + ic)*9 + t]);
    } else if (idx < 258048) {
        int j = idx - 36864;
        int s = 1 + j / 73728;
        int r = j % 73728;
        int blk = r >> 12;              // 0..17
        int r3  = r & 4095;
        int ocM = r3 >> 5, icl = r3 & 31;
        int cc = blk / 9, t = blk - 9*cc;
        int ic = cc*32 + icl;
        int oc = ocM >> 1, set = ocM & 1;
        const float* wsrc = (s == 1) ? w1 : (s == 2 ? w2 : w3);
        AH[idx] = f2bf(wsrc[(oc*64 + ic)*9 + t] * chm[(ic*4 + s)*2 + set]);
    } else {
        int r = idx - 258048;           // < 16384
        pwA[r] = f2bf(wc[r]);
    }
}

// ---------------------------------------------------------------------------
// MFMA conv, pure bf16. Block = one (b,h) row, 128 px. M = 64*NSETS rows
// (dense/sparse interleaved ocM = 2*oc+set). 4 waves as 2(M) x 2(N).
// B tile (input row triplet, [row][col][ic] stride 36) in LDS per 32-ic chunk.
// Staging: vectorized 16B/lane loads, pow2 index decomposition, split
// issue-phase / scatter-phase. Halo cols+rows are zeroed ONCE at block start
// (they are invariant zeros) instead of per-element predication.
// A frags stream L2 -> registers (coalesced dwordx4), pipelined 1 tap ahead.
// No barriers inside the 9-tap loop.
template<int NSETS, bool INF32>
__global__ __launch_bounds__(256, 2) void conv_bf16(
    const void* __restrict__ inv, const ushort* __restrict__ A,
    const float* __restrict__ chm, const float* __restrict__ spa,
    ushort* __restrict__ feaOut, int stage)
{
    constexpr int MOC = 64*NSETS;
    constexpr int MT  = MOC/32;     // m-tiles per wave
    __shared__ __align__(16) ushort sB[3*130*36]; // 28080 B

    const int tid  = threadIdx.x;
    const int lane = tid & 63, wave = tid >> 6;
    const int wrow = wave >> 1, wcol = wave & 1;
    const int q = lane >> 4, ln16 = lane & 15;
    const int h = blockIdx.x & 127, b = blockIdx.x >> 7;

    // zero-init whole tile once: covers halo cols (gw=-1,128) and any
    // out-of-range rows (gh<0 or >127); per-chunk staging only writes
    // in-range data so these stay zero for both chunks.
    {
        v8s z = (v8s){0,0,0,0,0,0,0,0};
        for (int e = tid; e < 1755; e += 256)      // 1755*8 = 14040 ushorts
            *(v8s*)(void*)(sB + e*8) = z;
    }

    v4f acc[MT][4];
    #pragma unroll
    for (int m = 0; m < MT; ++m)
        #pragma unroll
        for (int n = 0; n < 4; ++n) acc[m][n] = (v4f){0.f, 0.f, 0.f, 0.f};

    int aRow[MT];
    #pragma unroll
    for (int m = 0; m < MT; ++m)
        aRow[m] = (wrow*(MOC/2) + m*16 + ln16)*32 + q*8;

    for (int c = 0; c < 2; ++c) {
        const int ic0 = c*32;
        __syncthreads();
        // ---- stage 3 rows x 32 ic x 128 w, 16B/lane, 6 iters/thread ----
        {
            v8s stg[6];
            #pragma unroll
            for (int it = 0; it < 6; ++it) {
                int i  = it*256 + tid;     // [0,1536)
                int ry = i >> 9;           // 0..2
                int r  = i & 511;
                int ic = r >> 4, wv = r & 15;
                int gh = h - 1 + ry;
                v8s v = (v8s){0,0,0,0,0,0,0,0};
                if ((unsigned)gh < 128u) {
                    size_t gi = (size_t)((b*C_ + ic0 + ic)*H_ + gh)*W_ + wv*8;
                    if constexpr (INF32) {
                        const float* s = (const float*)inv + gi;
                        v4f a0 = *(const v4f*)(const void*)s;
                        v4f a1 = *(const v4f*)(const void*)(s + 4);
                        #pragma unroll
                        for (int j = 0; j < 4; ++j) {
                            v[j]   = (short)f2bf(a0[j]);
                            v[4+j] = (short)f2bf(a1[j]);
                        }
                    } else {
                        v = *(const v8s*)(const void*)((const ushort*)inv + gi);
                    }
                }
                stg[it] = v;
            }
            #pragma unroll
            for (int it = 0; it < 6; ++it) {
                int i  = it*256 + tid;
                int ry = i >> 9;
                int r  = i & 511;
                int ic = r >> 4, wv = r & 15;
                ushort* dst = &sB[(ry*130 + wv*8 + 1)*36 + ic];
                #pragma unroll
                for (int j = 0; j < 8; ++j) dst[j*36] = (ushort)stg[it][j];
            }
        }
        __syncthreads();

        const ushort* Ab = A + c*9*MOC*32;
        v8s af[MT];
        #pragma unroll
        for (int m = 0; m < MT; ++m)
            af[m] = *(const v8s*)(const void*)(Ab + aRow[m]);

        #pragma unroll
        for (int t = 0; t < 9; ++t) {
            v8s afn[MT];
            if (t < 8) {
                #pragma unroll
                for (int m = 0; m < MT; ++m)
                    afn[m] = *(const v8s*)(const void*)(Ab + (t+1)*MOC*32 + aRow[m]);
            }
            const int ky = t/3, kx = t - 3*(t/3);
            #pragma unroll
            for (int nt = 0; nt < 4; ++nt) {
                int col = wcol*64 + nt*16 + ln16 + kx;
                v8s bf = ld_b64x2(&sB[(ky*130 + col)*36 + q*8]);
                #pragma unroll
                for (int m = 0; m < MT; ++m)
                    acc[m][nt] = __builtin_amdgcn_mfma_f32_16x16x32_bf16(af[m], bf, acc[m][nt], 0, 0, 0);
            }
            if (t < 8) {
                #pragma unroll
                for (int m = 0; m < MT; ++m) af[m] = afn[m];
            }
        }
    }

    // epilogue: gates + relu, bf16 store
    const float* spaRow = &spa[b*HW_ + h*W_];
    #pragma unroll
    for (int nt = 0; nt < 4; ++nt) {
        int px = wcol*64 + nt*16 + ln16;
        float sp = spaRow[px];
        #pragma unroll
        for (int m = 0; m < MT; ++m) {
            if constexpr (NSETS == 2) {
                #pragma unroll
                for (int rp = 0; rp < 2; ++rp) {
                    int oc = wrow*32 + m*8 + q*2 + rp;
                    float md = chm[(oc*4 + stage)*2 + 0];
                    float ms = chm[(oc*4 + stage)*2 + 1];
                    float f = acc[m][nt][2*rp]*(ms*sp + md)
                            + acc[m][nt][2*rp+1]*((ms + md)*sp);
                    feaOut[((size_t)(b*C_ + oc)*H_ + h)*W_ + px] = f2bf(fmaxf(f, 0.f));
                }
            } else {
                #pragma unroll
                for (int r = 0; r < 4; ++r) {
                    int oc = wrow*32 + m*16 + q*4 + r;
                    float md = chm[(oc*4 + stage)*2 + 0];
                    float ms = chm[(oc*4 + stage)*2 + 1];
                    float f = acc[m][nt][r]*(ms*sp + md);
                    feaOut[((size_t)(b*C_ + oc)*H_ + h)*W_ + px] = f2bf(fmaxf(f, 0.f));
                }
            }
        }
    }
}

// ---------------------------------------------------------------------------
// Final pointwise: out[b,o,px] = sum_{k=0..255} wc[o][k]*fea_{k/64}[k%64][px] + bc[o]
// Block = 64 px of one (b,h) row. MFMA: M=64, N=64, K=256.
// Staging vectorized: 16B/lane, 8 iters/thread, split issue/scatter phases.
__global__ __launch_bounds__(256, 2) void pw_final(
    const ushort* __restrict__ fea, const ushort* __restrict__ pwA,
    const float* __restrict__ bc, float* __restrict__ out)
{
    __shared__ __align__(16) ushort sF[64*260];   // 33280 B, [px][k] stride 260

    const int tid  = threadIdx.x;
    const int lane = tid & 63, wave = tid >> 6;
    const int wrow = wave >> 1, wcol = wave & 1;
    const int q = lane >> 4, ln16 = lane & 15;
    const int half = blockIdx.x & 1;
    const int h = (blockIdx.x >> 1) & 127;
    const int b = blockIdx.x >> 8;
    const int px0 = half*64;

    {
        v8s stg[8];
        #pragma unroll
        for (int it = 0; it < 8; ++it) {
            int i  = it*256 + tid;   // [0,2048)
            int s  = i >> 9;
            int r  = i & 511;
            int ic = r >> 3, pxv = r & 7;
            stg[it] = *(const v8s*)(const void*)(
                fea + (size_t)s*OUT_ELEMS + ((size_t)(b*C_ + ic)*H_ + h)*W_ + px0 + pxv*8);
        }
        #pragma unroll
        for (int it = 0; it < 8; ++it) {
            int i  = it*256 + tid;
            int s  = i >> 9;
            int r  = i & 511;
            int ic = r >> 3, pxv = r & 7;
            ushort* dst = &sF[(pxv*8)*260 + s*64 + ic];
            #pragma unroll
            for (int j = 0; j < 8; ++j) dst[j*260] = (ushort)stg[it][j];
        }
    }
    __syncthreads();

    v4f acc[2][2];
    #pragma unroll
    for (int m = 0; m < 2; ++m)
        #pragma unroll
        for (int n = 0; n < 2; ++n) acc[m][n] = (v4f){0.f, 0.f, 0.f, 0.f};

    #pragma unroll
    for (int ks = 0; ks < 8; ++ks) {
        v8s a[2];
        #pragma unroll
        for (int m = 0; m < 2; ++m)
            a[m] = *(const v8s*)(const void*)(pwA + (wrow*32 + m*16 + ln16)*256 + ks*32 + q*8);
        #pragma unroll
        for (int n = 0; n < 2; ++n) {
            int px = wcol*32 + n*16 + ln16;
            v8s bf = ld_b64x2(&sF[px*260 + ks*32 + q*8]);
            #pragma unroll
            for (int m = 0; m < 2; ++m)
                acc[m][n] = __builtin_amdgcn_mfma_f32_16x16x32_bf16(a[m], bf, acc[m][n], 0, 0, 0);
        }
    }

    #pragma unroll
    for (int n = 0; n < 2; ++n) {
        int px = px0 + wcol*32 + n*16 + ln16;
        #pragma unroll
        for (int m = 0; m < 2; ++m)
            #pragma unroll
            for (int r = 0; r < 4; ++r) {
                int o = wrow*32 + m*16 + q*4 + r;
                out[((size_t)(b*C_ + o)*H_ + h)*W_ + px] = acc[m][n][r] + bc[o];
            }
    }
}

// ---------------------------------------------------------------------------
extern "C" void kernel_launch(void* const* d_in, const int* in_sizes, int n_in,
                              void* d_out, int out_size, void* d_ws, size_t ws_size,
                              hipStream_t stream)
{
    const float* x0  = (const float*)d_in[0];
    const float* spa = (const float*)d_in[1];
    const float* gum = (const float*)d_in[2];
    const float* par = (const float*)d_in[3];
    const float* w0  = (const float*)d_in[4];
    const float* w1  = (const float*)d_in[5];
    const float* w2  = (const float*)d_in[6];
    const float* w3  = (const float*)d_in[7];
    const float* wc  = (const float*)d_in[8];
    const float* bc  = (const float*)d_in[9];
    float* out = (float*)d_out;
    char*  ws  = (char*)d_ws;

    float*  chm = (float*)(ws + CHM_B);
    ushort* pwA = (ushort*)(ws + PWA_B);
    ushort* AH  = (ushort*)(ws + AH_B);
    ushort* fea0 = (ushort*)(ws + FEA_B(0));
    ushort* fea1 = (ushort*)(ws + FEA_B(1));
    ushort* fea2 = (ushort*)(ws + FEA_B(2));
    ushort* fea3 = (ushort*)(ws + FEA_B(3));

    mask_kernel<<<1, 64, 0, stream>>>(gum, par, chm, out + OUT_ELEMS);
    prep_kernel<<<1072, 256, 0, stream>>>(w0, w1, w2, w3, wc, chm, AH, pwA);

    conv_bf16<1, true ><<<2048, 256, 0, stream>>>(x0,   AH + A_S0,  chm, spa, fea0, 0);
    conv_bf16<2, false><<<2048, 256, 0, stream>>>(fea0, AH + A_S(1), chm, spa, fea1, 1);
    conv_bf16<2, false><<<2048, 256, 0, stream>>>(fea1, AH + A_S(2), chm, spa, fea2, 2);
    conv_bf16<2, false><<<2048, 256, 0, stream>>>(fea2, AH + A_S(3), chm, spa, fea3, 3);

    pw_final<<<4096, 256, 0, stream>>>(fea0, pwA, bc, out);
}

// Round 2
// 426.825 us; speedup vs baseline: 1.6920x; 1.0252x over previous
//
#include <hip/hip_runtime.h>
#include <math.h>

// Problem constants
#define B_ 16
#define C_ 64
#define H_ 128
#define W_ 128
#define HW_ (H_*W_)
#define OUT_ELEMS 16777216   // B*C*H*W

// Workspace byte offsets
#define CHM_B    0                      // 512 f32
#define PWA_B    2048                   // 16384 u16
#define AH_B     34816                  // 258048 u16
#define FEA_B(s) (550912u + (size_t)(s)*33554432u)  // 4 x 16777216 u16

// A-image u16 offsets within AH
#define A_S0   0
#define A_S(s) (36864 + ((s)-1)*73728)  // s = 1..3

typedef __attribute__((ext_vector_type(4))) short  v4s;
typedef __attribute__((ext_vector_type(8))) short  v8s;
typedef __attribute__((ext_vector_type(4))) float  v4f;

__device__ __forceinline__ ushort f2bf(float f) {
    unsigned u = __builtin_bit_cast(unsigned, f);
    unsigned r = u + 0x7FFFu + ((u >> 16) & 1u);
    return (ushort)(r >> 16);
}
__device__ __forceinline__ v8s ld_b64x2(const ushort* p) {  // 8B-aligned
    v4s a = *(const v4s*)(const void*)p;
    v4s b = *(const v4s*)(const void*)(p + 4);
    return __builtin_shufflevector(a, b, 0, 1, 2, 3, 4, 5, 6, 7);
}

// ---------------------------------------------------------------------------
__global__ __launch_bounds__(64) void mask_kernel(
    const float* __restrict__ gum, const float* __restrict__ par,
    float* __restrict__ chm, float* __restrict__ out_tail)
{
    int c = threadIdx.x;
    #pragma unroll
    for (int i = 0; i < 4; ++i) {
        int base = (c*4 + i)*2;
        float g0 = -logf(-logf(gum[base]));
        float g1 = -logf(-logf(gum[base+1]));
        float a0 = par[base] + g0, a1 = par[base+1] + g1;
        float mx = fmaxf(a0, a1);
        float e0 = expf(a0 - mx), e1 = expf(a1 - mx);
        float inv = 1.0f / (e0 + e1);
        float m0 = e0*inv, m1 = e1*inv;
        chm[base] = m0; chm[base+1] = m1;
        out_tail[base] = m0; out_tail[base+1] = m1;
    }
}

// ---------------------------------------------------------------------------
// Build bf16 A-images (gate-folded weights) + bf16 pw weights.
__global__ __launch_bounds__(256) void prep_kernel(
    const float* __restrict__ w0, const float* __restrict__ w1,
    const float* __restrict__ w2, const float* __restrict__ w3,
    const float* __restrict__ wc, const float* __restrict__ chm,
    ushort* __restrict__ AH, ushort* __restrict__ pwA)
{
    int idx = blockIdx.x*256 + threadIdx.x;   // < 274432
    if (idx < 36864) {
        int blk = idx >> 11;            // c*9+t, 0..17
        int r3  = idx & 2047;
        int oc = r3 >> 5, icl = r3 & 31;
        int cc = blk / 9, t = blk - 9*cc;
        int ic = cc*32 + icl;
        AH[idx] = f2bf(w0[(oc*64 + ic)*9 + t]);
    } else if (idx < 258048) {
        int j = idx - 36864;
        int s = 1 + j / 73728;
        int r = j % 73728;
        int blk = r >> 12;              // 0..17
        int r3  = r & 4095;
        int ocM = r3 >> 5, icl = r3 & 31;
        int cc = blk / 9, t = blk - 9*cc;
        int ic = cc*32 + icl;
        int oc = ocM >> 1, set = ocM & 1;
        const float* wsrc = (s == 1) ? w1 : (s == 2 ? w2 : w3);
        AH[idx] = f2bf(wsrc[(oc*64 + ic)*9 + t] * chm[(ic*4 + s)*2 + set]);
    } else {
        int r = idx - 258048;           // < 16384
        pwA[r] = f2bf(wc[r]);
    }
}

// ---------------------------------------------------------------------------
// MFMA conv, pure bf16. Block = one (b,h) row, 128 px. M = 64*NSETS rows
// (dense/sparse interleaved ocM = 2*oc+set). 4 waves as 2(M) x 2(N).
// LDS B tile layout: sB[colIdx*36 + (ic ^ ((colIdx>>3 & 3)<<3))]  (XOR swizzle
// spreads the transpose-scatter writes across ~16 banks instead of 2; reads
// stay contiguous-8 since the XOR only touches ic bits 3-4).
// T14: chunk-1 global loads issued before chunk-0 compute (latency hidden).
// A frags: 3-buffer rotating prefetch, 2 taps ahead (covers ~200cy L2 lat).
// XCD-swizzled blockIdx: contiguous h-ranges per XCD -> halo rows L2-local.
template<int NSETS, bool INF32>
__global__ __launch_bounds__(256, 2) void conv_bf16(
    const void* __restrict__ inv, const ushort* __restrict__ A,
    const float* __restrict__ chm, const float* __restrict__ spa,
    ushort* __restrict__ feaOut, int stage)
{
    constexpr int MOC = 64*NSETS;
    constexpr int MT  = MOC/32;     // m-tiles per wave
    __shared__ __align__(16) ushort sB[3*130*36]; // 28080 B

    const int tid  = threadIdx.x;
    const int lane = tid & 63, wave = tid >> 6;
    const int wrow = wave >> 1, wcol = wave & 1;
    const int q = lane >> 4, ln16 = lane & 15;
    // XCD-aware remap: HW round-robins blockIdx across 8 XCDs; give each XCD
    // a contiguous chunk of (b,h) space so neighboring rows share L2.
    const int wk = (blockIdx.x & 7)*256 + (blockIdx.x >> 3);   // grid = 2048
    const int h = wk & 127, b = wk >> 7;

    // zero-init whole tile once: covers halo cols (gw=-1,128) and
    // out-of-range rows; staging only writes in-range interior.
    {
        v8s z = (v8s){0,0,0,0,0,0,0,0};
        for (int e = tid; e < 1755; e += 256)      // 1755*8 = 14040 ushorts
            *(v8s*)(void*)(sB + e*8) = z;
    }

    v4f acc[MT][4];
    #pragma unroll
    for (int m = 0; m < MT; ++m)
        #pragma unroll
        for (int n = 0; n < 4; ++n) acc[m][n] = (v4f){0.f, 0.f, 0.f, 0.f};

    int aRow[MT];
    #pragma unroll
    for (int m = 0; m < MT; ++m)
        aRow[m] = (wrow*(MOC/2) + m*16 + ln16)*32 + q*8;

    // -------- staging helpers (registers only; no LDS, no barriers) --------
    v8s stgA[6], stgB[6];
    v4f stgAF[12], stgBF[12];

    auto issue = [&](int ic0, v8s* stg, v4f* stgF) {
        #pragma unroll
        for (int it = 0; it < 6; ++it) {
            int i  = it*256 + tid;     // [0,1536)
            int ry = i >> 9;           // 0..2
            int r  = i & 511;
            int ic = r >> 4, wv = r & 15;
            int gh = h - 1 + ry;
            if constexpr (INF32) {
                v4f a0 = (v4f){0.f,0.f,0.f,0.f}, a1 = a0;
                if ((unsigned)gh < 128u) {
                    const float* s = (const float*)inv +
                        ((size_t)((b*C_ + ic0 + ic)*H_ + gh)*W_ + wv*8);
                    a0 = *(const v4f*)(const void*)s;
                    a1 = *(const v4f*)(const void*)(s + 4);
                }
                stgF[it*2] = a0; stgF[it*2+1] = a1;
            } else {
                v8s v = (v8s){0,0,0,0,0,0,0,0};
                if ((unsigned)gh < 128u)
                    v = *(const v8s*)(const void*)((const ushort*)inv +
                        ((size_t)((b*C_ + ic0 + ic)*H_ + gh)*W_ + wv*8));
                stg[it] = v;
            }
        }
    };
    auto scatter = [&](const v8s* stg, const v4f* stgF) {
        #pragma unroll
        for (int it = 0; it < 6; ++it) {
            int i  = it*256 + tid;
            int ry = i >> 9;
            int r  = i & 511;
            int ic = r >> 4, wv = r & 15;
            int colBase = ry*130 + wv*8 + 1;
            ushort vals[8];
            if constexpr (INF32) {
                #pragma unroll
                for (int j = 0; j < 4; ++j) {
                    vals[j]   = f2bf(stgF[it*2][j]);
                    vals[4+j] = f2bf(stgF[it*2+1][j]);
                }
            } else {
                #pragma unroll
                for (int j = 0; j < 8; ++j) vals[j] = (ushort)stg[it][j];
            }
            #pragma unroll
            for (int j = 0; j < 8; ++j) {
                int colIdx = colBase + j;
                sB[colIdx*36 + (ic ^ (((colIdx >> 3) & 3) << 3))] = vals[j];
            }
        }
    };
    auto compute = [&](const ushort* Ab) {
        v8s af0[MT], af1[MT], af2[MT];
        #pragma unroll
        for (int m = 0; m < MT; ++m)
            af0[m] = *(const v8s*)(const void*)(Ab + aRow[m]);
        #pragma unroll
        for (int m = 0; m < MT; ++m)
            af1[m] = *(const v8s*)(const void*)(Ab + MOC*32 + aRow[m]);
        #pragma unroll
        for (int t = 0; t < 9; ++t) {
            if (t < 7) {
                #pragma unroll
                for (int m = 0; m < MT; ++m)
                    af2[m] = *(const v8s*)(const void*)(Ab + (t+2)*MOC*32 + aRow[m]);
            }
            const int ky = t/3, kx = t - 3*(t/3);
            #pragma unroll
            for (int nt = 0; nt < 4; ++nt) {
                int colIdx = ky*130 + wcol*64 + nt*16 + ln16 + kx;
                v8s bf = ld_b64x2(&sB[colIdx*36 + ((q ^ ((colIdx >> 3) & 3)) << 3)]);
                #pragma unroll
                for (int m = 0; m < MT; ++m)
                    acc[m][nt] = __builtin_amdgcn_mfma_f32_16x16x32_bf16(af0[m], bf, acc[m][nt], 0, 0, 0);
            }
            #pragma unroll
            for (int m = 0; m < MT; ++m) { af0[m] = af1[m]; af1[m] = af2[m]; }
        }
    };

    // -------- schedule --------
    issue(0, stgA, stgAF);
    __syncthreads();                 // zero-init complete
    scatter(stgA, stgAF);
    issue(32, stgB, stgBF);          // T14: chunk-1 loads fly under chunk-0 compute
    __syncthreads();                 // chunk-0 tile ready
    compute(A);
    __syncthreads();                 // chunk-0 reads done
    scatter(stgB, stgBF);
    __syncthreads();                 // chunk-1 tile ready
    compute(A + 9*MOC*32);

    // epilogue: gates + relu, bf16 store
    const float* spaRow = &spa[b*HW_ + h*W_];
    #pragma unroll
    for (int nt = 0; nt < 4; ++nt) {
        int px = wcol*64 + nt*16 + ln16;
        float sp = spaRow[px];
        #pragma unroll
        for (int m = 0; m < MT; ++m) {
            if constexpr (NSETS == 2) {
                #pragma unroll
                for (int rp = 0; rp < 2; ++rp) {
                    int oc = wrow*32 + m*8 + q*2 + rp;
                    float md = chm[(oc*4 + stage)*2 + 0];
                    float ms = chm[(oc*4 + stage)*2 + 1];
                    float f = acc[m][nt][2*rp]*(ms*sp + md)
                            + acc[m][nt][2*rp+1]*((ms + md)*sp);
                    feaOut[((size_t)(b*C_ + oc)*H_ + h)*W_ + px] = f2bf(fmaxf(f, 0.f));
                }
            } else {
                #pragma unroll
                for (int r = 0; r < 4; ++r) {
                    int oc = wrow*32 + m*16 + q*4 + r;
                    float md = chm[(oc*4 + stage)*2 + 0];
                    float ms = chm[(oc*4 + stage)*2 + 1];
                    float f = acc[m][nt][r]*(ms*sp + md);
                    feaOut[((size_t)(b*C_ + oc)*H_ + h)*W_ + px] = f2bf(fmaxf(f, 0.f));
                }
            }
        }
    }
}

// ---------------------------------------------------------------------------
// Final pointwise: out[b,o,px] = sum_{k=0..255} wc[o][k]*fea_{k/64}[k%64][px] + bc[o]
// Block = 64 px of one (b,h) row. MFMA: M=64, N=64, K=256.
// LDS layout swizzled: sF[px*260 + (k ^ ((px>>3 & 3)<<3))] — scatter writes
// spread across banks; reads remain contiguous-8.
__global__ __launch_bounds__(256, 2) void pw_final(
    const ushort* __restrict__ fea, const ushort* __restrict__ pwA,
    const float* __restrict__ bc, float* __restrict__ out)
{
    __shared__ __align__(16) ushort sF[64*260];   // 33280 B

    const int tid  = threadIdx.x;
    const int lane = tid & 63, wave = tid >> 6;
    const int wrow = wave >> 1, wcol = wave & 1;
    const int q = lane >> 4, ln16 = lane & 15;
    const int half = blockIdx.x & 1;
    const int h = (blockIdx.x >> 1) & 127;
    const int b = blockIdx.x >> 8;
    const int px0 = half*64;

    {
        v8s stg[8];
        #pragma unroll
        for (int it = 0; it < 8; ++it) {
            int i  = it*256 + tid;   // [0,2048)
            int s  = i >> 9;
            int r  = i & 511;
            int ic = r >> 3, pxv = r & 7;
            stg[it] = *(const v8s*)(const void*)(
                fea + (size_t)s*OUT_ELEMS + ((size_t)(b*C_ + ic)*H_ + h)*W_ + px0 + pxv*8);
        }
        #pragma unroll
        for (int it = 0; it < 8; ++it) {
            int i  = it*256 + tid;
            int s  = i >> 9;
            int r  = i & 511;
            int ic = r >> 3, pxv = r & 7;
            int kS = (s*64 + ic) ^ ((pxv & 3) << 3);    // px>>3 == pxv for j<8
            ushort* dst = &sF[(pxv*8)*260 + kS];
            #pragma unroll
            for (int j = 0; j < 8; ++j) dst[j*260] = (ushort)stg[it][j];
        }
    }
    __syncthreads();

    v4f acc[2][2];
    #pragma unroll
    for (int m = 0; m < 2; ++m)
        #pragma unroll
        for (int n = 0; n < 2; ++n) acc[m][n] = (v4f){0.f, 0.f, 0.f, 0.f};

    #pragma unroll
    for (int ks = 0; ks < 8; ++ks) {
        v8s a[2];
        #pragma unroll
        for (int m = 0; m < 2; ++m)
            a[m] = *(const v8s*)(const void*)(pwA + (wrow*32 + m*16 + ln16)*256 + ks*32 + q*8);
        #pragma unroll
        for (int n = 0; n < 2; ++n) {
            int px = wcol*32 + n*16 + ln16;
            int swz = (px >> 3) & 3;
            v8s bf = ld_b64x2(&sF[px*260 + ks*32 + ((q ^ swz) << 3)]);
            #pragma unroll
            for (int m = 0; m < 2; ++m)
                acc[m][n] = __builtin_amdgcn_mfma_f32_16x16x32_bf16(a[m], bf, acc[m][n], 0, 0, 0);
        }
    }

    #pragma unroll
    for (int n = 0; n < 2; ++n) {
        int px = px0 + wcol*32 + n*16 + ln16;
        #pragma unroll
        for (int m = 0; m < 2; ++m)
            #pragma unroll
            for (int r = 0; r < 4; ++r) {
                int o = wrow*32 + m*16 + q*4 + r;
                out[((size_t)(b*C_ + o)*H_ + h)*W_ + px] = acc[m][n][r] + bc[o];
            }
    }
}

// ---------------------------------------------------------------------------
extern "C" void kernel_launch(void* const* d_in, const int* in_sizes, int n_in,
                              void* d_out, int out_size, void* d_ws, size_t ws_size,
                              hipStream_t stream)
{
    const float* x0  = (const float*)d_in[0];
    const float* spa = (const float*)d_in[1];
    const float* gum = (const float*)d_in[2];
    const float* par = (const float*)d_in[3];
    const float* w0  = (const float*)d_in[4];
    const float* w1  = (const float*)d_in[5];
    const float* w2  = (const float*)d_in[6];
    const float* w3  = (const float*)d_in[7];
    const float* wc  = (const float*)d_in[8];
    const float* bc  = (const float*)d_in[9];
    float* out = (float*)d_out;
    char*  ws  = (char*)d_ws;

    float*  chm = (float*)(ws + CHM_B);
    ushort* pwA = (ushort*)(ws + PWA_B);
    ushort* AH  = (ushort*)(ws + AH_B);
    ushort* fea0 = (ushort*)(ws + FEA_B(0));
    ushort* fea1 = (ushort*)(ws + FEA_B(1));
    ushort* fea2 = (ushort*)(ws + FEA_B(2));
    ushort* fea3 = (ushort*)(ws + FEA_B(3));

    mask_kernel<<<1, 64, 0, stream>>>(gum, par, chm, out + OUT_ELEMS);
    prep_kernel<<<1072, 256, 0, stream>>>(w0, w1, w2, w3, wc, chm, AH, pwA);

    conv_bf16<1, true ><<<2048, 256, 0, stream>>>(x0,   AH + A_S0,  chm, spa, fea0, 0);
    conv_bf16<2, false><<<2048, 256, 0, stream>>>(fea0, AH + A_S(1), chm, spa, fea1, 1);
    conv_bf16<2, false><<<2048, 256, 0, stream>>>(fea1, AH + A_S(2), chm, spa, fea2, 2);
    conv_bf16<2, false><<<2048, 256, 0, stream>>>(fea2, AH + A_S(3), chm, spa, fea3, 3);

    pw_final<<<4096, 256, 0, stream>>>(fea0, pwA, bc, out);
}

// Round 4
// 417.668 us; speedup vs baseline: 1.7291x; 1.0219x over previous
//
#include <hip/hip_runtime.h>
#include <math.h>

// Problem constants
#define B_ 16
#define C_ 64
#define H_ 128
#define W_ 128
#define HW_ (H_*W_)
#define OUT_ELEMS 16777216   // B*C*H*W

// Workspace byte offsets
#define CHM_B    0                      // 512 f32
#define PWA_B    2048                   // 16384 u16
#define AH_B     34816                  // 258048 u16
#define FEA_B(s) (550912u + (size_t)(s)*33554432u)  // 4 x 16777216 u16

// A-image u16 offsets within AH
#define A_S0   0
#define A_S(s) (36864 + ((s)-1)*73728)  // s = 1..3

typedef __attribute__((ext_vector_type(4))) short  v4s;
typedef __attribute__((ext_vector_type(8))) short  v8s;
typedef __attribute__((ext_vector_type(4))) float  v4f;

__device__ __forceinline__ ushort f2bf(float f) {
    unsigned u = __builtin_bit_cast(unsigned, f);
    unsigned r = u + 0x7FFFu + ((u >> 16) & 1u);
    return (ushort)(r >> 16);
}

// ---------------------------------------------------------------------------
__global__ __launch_bounds__(64) void mask_kernel(
    const float* __restrict__ gum, const float* __restrict__ par,
    float* __restrict__ chm, float* __restrict__ out_tail)
{
    int c = threadIdx.x;
    #pragma unroll
    for (int i = 0; i < 4; ++i) {
        int base = (c*4 + i)*2;
        float g0 = -logf(-logf(gum[base]));
        float g1 = -logf(-logf(gum[base+1]));
        float a0 = par[base] + g0, a1 = par[base+1] + g1;
        float mx = fmaxf(a0, a1);
        float e0 = expf(a0 - mx), e1 = expf(a1 - mx);
        float inv = 1.0f / (e0 + e1);
        float m0 = e0*inv, m1 = e1*inv;
        chm[base] = m0; chm[base+1] = m1;
        out_tail[base] = m0; out_tail[base+1] = m1;
    }
}

// ---------------------------------------------------------------------------
// Build bf16 A-images (gate-folded weights) + bf16 pw weights.
__global__ __launch_bounds__(256) void prep_kernel(
    const float* __restrict__ w0, const float* __restrict__ w1,
    const float* __restrict__ w2, const float* __restrict__ w3,
    const float* __restrict__ wc, const float* __restrict__ chm,
    ushort* __restrict__ AH, ushort* __restrict__ pwA)
{
    int idx = blockIdx.x*256 + threadIdx.x;   // < 274432
    if (idx < 36864) {
        int blk = idx >> 11;            // c*9+t, 0..17
        int r3  = idx & 2047;
        int oc = r3 >> 5, icl = r3 & 31;
        int cc = blk / 9, t = blk - 9*cc;
        int ic = cc*32 + icl;
        AH[idx] = f2bf(w0[(oc*64 + ic)*9 + t]);
    } else if (idx < 258048) {
        int j = idx - 36864;
        int s = 1 + j / 73728;
        int r = j % 73728;
        int blk = r >> 12;              // 0..17
        int r3  = r & 4095;
        int ocM = r3 >> 5, icl = r3 & 31;
        int cc = blk / 9, t = blk - 9*cc;
        int ic = cc*32 + icl;
        int oc = ocM >> 1, set = ocM & 1;
        const float* wsrc = (s == 1) ? w1 : (s == 2 ? w2 : w3);
        AH[idx] = f2bf(wsrc[(oc*64 + ic)*9 + t] * chm[(ic*4 + s)*2 + set]);
    } else {
        int r = idx - 258048;           // < 16384
        pwA[r] = f2bf(wc[r]);
    }
}

// ---------------------------------------------------------------------------
// MFMA conv, pure bf16. Block = one (b,h) row, 128 px. M = 64*NSETS rows.
// LDS layout: sB[colIdx*36 + (ic ^ (((colIdx>>3)&7)<<2))] — 3-bit XOR swizzle
// on ic bits 2-4, keyed on colIdx bits 3-5. Scatter writes: ~4-way conflict.
// Reads: two aligned b64 loads at base+((s3&1)<<2) and its ^4 partner,
// reassembled in jj order (algebra: (q*8+jj)^(s3<<2) splits into two 4-runs).
// Halo zero-init touches ONLY columns {ry*130+0, ry*130+129} — provably
// disjoint from scatter (which writes cols 1..128; OOB rows get explicit
// zeros from zeroed staging regs). No barrier needed between them.
// A frags: ring-4 (3-tap-ahead) prefetch, compile-time ring indices.
// Staging regs reused chunk0->chunk1 (issue(32) flies under barrier+compute).
template<int NSETS, bool INF32>
__global__ __launch_bounds__(256, 2) void conv_bf16(
    const void* __restrict__ inv, const ushort* __restrict__ A,
    const float* __restrict__ chm, const float* __restrict__ spa,
    ushort* __restrict__ feaOut, int stage)
{
    constexpr int MOC = 64*NSETS;
    constexpr int MT  = MOC/32;     // m-tiles per wave
    __shared__ __align__(16) ushort sB[3*130*36]; // 28080 B

    const int tid  = threadIdx.x;
    const int lane = tid & 63, wave = tid >> 6;
    const int wrow = wave >> 1, wcol = wave & 1;
    const int q = lane >> 4, ln16 = lane & 15;
    // XCD-aware remap (grid 2048 = 8*256): contiguous (b,h) chunk per XCD.
    const int wk = (blockIdx.x & 7)*256 + (blockIdx.x >> 3);
    const int h = wk & 127, b = wk >> 7;

    v4f acc[MT][4];
    #pragma unroll
    for (int m = 0; m < MT; ++m)
        #pragma unroll
        for (int n = 0; n < 4; ++n) acc[m][n] = (v4f){0.f, 0.f, 0.f, 0.f};

    int aRow[MT];
    #pragma unroll
    for (int m = 0; m < MT; ++m)
        aRow[m] = (wrow*(MOC/2) + m*16 + ln16)*32 + q*8;

    // staging registers (reused across chunks) + A-frag ring
    v8s stg[6];
    v4f stgF[12];
    v8s af[4][MT];

    auto issue = [&](int ic0) {
        #pragma unroll
        for (int it = 0; it < 6; ++it) {
            int i  = it*256 + tid;     // [0,1536)
            int ry = i >> 9;           // 0..2
            int r  = i & 511;
            int ic = r >> 4, wv = r & 15;
            int gh = h - 1 + ry;
            if constexpr (INF32) {
                v4f a0 = (v4f){0.f,0.f,0.f,0.f}, a1 = a0;
                if ((unsigned)gh < 128u) {
                    const float* s = (const float*)inv +
                        ((size_t)((b*C_ + ic0 + ic)*H_ + gh)*W_ + wv*8);
                    a0 = *(const v4f*)(const void*)s;
                    a1 = *(const v4f*)(const void*)(s + 4);
                }
                stgF[it*2] = a0; stgF[it*2+1] = a1;
            } else {
                v8s v = (v8s){0,0,0,0,0,0,0,0};
                if ((unsigned)gh < 128u)
                    v = *(const v8s*)(const void*)((const ushort*)inv +
                        ((size_t)((b*C_ + ic0 + ic)*H_ + gh)*W_ + wv*8));
                stg[it] = v;
            }
        }
    };
    auto scatter = [&]() {
        #pragma unroll
        for (int it = 0; it < 6; ++it) {
            int i  = it*256 + tid;
            int ry = i >> 9;
            int r  = i & 511;
            int ic = r >> 4, wv = r & 15;
            int colBase = ry*130 + wv*8 + 1;
            ushort vals[8];
            if constexpr (INF32) {
                #pragma unroll
                for (int j = 0; j < 4; ++j) {
                    vals[j]   = f2bf(stgF[it*2][j]);
                    vals[4+j] = f2bf(stgF[it*2+1][j]);
                }
            } else {
                #pragma unroll
                for (int j = 0; j < 8; ++j) vals[j] = (ushort)stg[it][j];
            }
            #pragma unroll
            for (int j = 0; j < 8; ++j) {
                int colIdx = colBase + j;
                int s3 = (colIdx >> 3) & 7;
                sB[colIdx*36 + (ic ^ (s3 << 2))] = vals[j];
            }
        }
    };
    auto prolog = [&](const ushort* Ab) {
        #pragma unroll
        for (int tp = 0; tp < 3; ++tp)
            #pragma unroll
            for (int m = 0; m < MT; ++m)
                af[tp][m] = *(const v8s*)(const void*)(Ab + tp*MOC*32 + aRow[m]);
    };
    auto compute = [&](const ushort* Ab) {
        #pragma unroll
        for (int t = 0; t < 9; ++t) {
            if (t < 6) {
                #pragma unroll
                for (int m = 0; m < MT; ++m)
                    af[(t+3)&3][m] = *(const v8s*)(const void*)(Ab + (t+3)*MOC*32 + aRow[m]);
            }
            const int ky = t/3, kx = t - 3*(t/3);
            #pragma unroll
            for (int nt = 0; nt < 4; ++nt) {
                int colIdx = ky*130 + wcol*64 + nt*16 + ln16 + kx;
                int s3 = (colIdx >> 3) & 7;
                int base = colIdx*36 + ((q ^ (s3 >> 1)) << 3);
                int lo = base + ((s3 & 1) << 2);
                int hi = base + (((s3 & 1) ^ 1) << 2);
                v4s va = *(const v4s*)(const void*)(sB + lo);   // ic jj 0..3
                v4s vb = *(const v4s*)(const void*)(sB + hi);   // ic jj 4..7
                v8s bf = __builtin_shufflevector(va, vb, 0, 1, 2, 3, 4, 5, 6, 7);
                #pragma unroll
                for (int m = 0; m < MT; ++m)
                    acc[m][nt] = __builtin_amdgcn_mfma_f32_16x16x32_bf16(af[t&3][m], bf, acc[m][nt], 0, 0, 0);
            }
        }
    };

    // -------- schedule --------
    issue(0);                 // chunk-0 fea loads in flight
    prolog(A);                // chunk-0 A taps 0-2 in flight
    // zero ONLY halo columns colIdx = ry*130 + {0,129} (216 u16 total).
    // Scatter never writes these; they stay zero for both chunks.
    if (tid < 216) {
        int colSel = tid / 36;          // 0..5
        int icz    = tid - colSel*36;   // 0..35
        int ry     = colSel >> 1;
        int colIdx = ry*130 + ((colSel & 1) ? 129 : 0);
        sB[colIdx*36 + icz] = 0;
    }
    scatter();                // waits chunk-0 fea; disjoint from halo zeroes
    issue(32);                // chunk-1 fea flies under barrier+compute
    __syncthreads();          // tile 0 ready (zeroes + scatter visible)
    compute(A);
    prolog(A + 9*MOC*32);     // chunk-1 A taps 0-2 in flight
    __syncthreads();          // tile-0 reads done
    scatter();                // chunk-1 (regs already landed)
    __syncthreads();          // tile 1 ready
    compute(A + 9*MOC*32);

    // epilogue: gates + relu, bf16 store
    const float* spaRow = &spa[b*HW_ + h*W_];
    #pragma unroll
    for (int nt = 0; nt < 4; ++nt) {
        int px = wcol*64 + nt*16 + ln16;
        float sp = spaRow[px];
        #pragma unroll
        for (int m = 0; m < MT; ++m) {
            if constexpr (NSETS == 2) {
                #pragma unroll
                for (int rp = 0; rp < 2; ++rp) {
                    int oc = wrow*32 + m*8 + q*2 + rp;
                    float md = chm[(oc*4 + stage)*2 + 0];
                    float ms = chm[(oc*4 + stage)*2 + 1];
                    float f = acc[m][nt][2*rp]*(ms*sp + md)
                            + acc[m][nt][2*rp+1]*((ms + md)*sp);
                    feaOut[((size_t)(b*C_ + oc)*H_ + h)*W_ + px] = f2bf(fmaxf(f, 0.f));
                }
            } else {
                #pragma unroll
                for (int r = 0; r < 4; ++r) {
                    int oc = wrow*32 + m*16 + q*4 + r;
                    float md = chm[(oc*4 + stage)*2 + 0];
                    float ms = chm[(oc*4 + stage)*2 + 1];
                    float f = acc[m][nt][r]*(ms*sp + md);
                    feaOut[((size_t)(b*C_ + oc)*H_ + h)*W_ + px] = f2bf(fmaxf(f, 0.f));
                }
            }
        }
    }
}

// ---------------------------------------------------------------------------
// Final pointwise: out[b,o,px] = sum_{k=0..255} wc[o][k]*fea_{k/64}[k%64][px] + bc[o]
// Block = 64 px of one (b,h) row. MFMA: M=64, N=64, K=256.
__global__ __launch_bounds__(256, 2) void pw_final(
    const ushort* __restrict__ fea, const ushort* __restrict__ pwA,
    const float* __restrict__ bc, float* __restrict__ out)
{
    __shared__ __align__(16) ushort sF[64*260];   // 33280 B

    const int tid  = threadIdx.x;
    const int lane = tid & 63, wave = tid >> 6;
    const int wrow = wave >> 1, wcol = wave & 1;
    const int q = lane >> 4, ln16 = lane & 15;
    const int half = blockIdx.x & 1;
    const int h = (blockIdx.x >> 1) & 127;
    const int b = blockIdx.x >> 8;
    const int px0 = half*64;

    {
        v8s stg[8];
        #pragma unroll
        for (int it = 0; it < 8; ++it) {
            int i  = it*256 + tid;   // [0,2048)
            int s  = i >> 9;
            int r  = i & 511;
            int ic = r >> 3, pxv = r & 7;
            stg[it] = *(const v8s*)(const void*)(
                fea + (size_t)s*OUT_ELEMS + ((size_t)(b*C_ + ic)*H_ + h)*W_ + px0 + pxv*8);
        }
        #pragma unroll
        for (int it = 0; it < 8; ++it) {
            int i  = it*256 + tid;
            int s  = i >> 9;
            int r  = i & 511;
            int ic = r >> 3, pxv = r & 7;
            int kS = (s*64 + ic) ^ ((pxv & 3) << 3);
            ushort* dst = &sF[(pxv*8)*260 + kS];
            #pragma unroll
            for (int j = 0; j < 8; ++j) dst[j*260] = (ushort)stg[it][j];
        }
    }
    __syncthreads();

    v4f acc[2][2];
    #pragma unroll
    for (int m = 0; m < 2; ++m)
        #pragma unroll
        for (int n = 0; n < 2; ++n) acc[m][n] = (v4f){0.f, 0.f, 0.f, 0.f};

    #pragma unroll
    for (int ks = 0; ks < 8; ++ks) {
        v8s a[2];
        #pragma unroll
        for (int m = 0; m < 2; ++m)
            a[m] = *(const v8s*)(const void*)(pwA + (wrow*32 + m*16 + ln16)*256 + ks*32 + q*8);
        #pragma unroll
        for (int n = 0; n < 2; ++n) {
            int px = wcol*32 + n*16 + ln16;
            int swz = (px >> 3) & 3;
            v4s va = *(const v4s*)(const void*)(sF + px*260 + ks*32 + ((q ^ swz) << 3));
            v4s vb = *(const v4s*)(const void*)(sF + px*260 + ks*32 + ((q ^ swz) << 3) + 4);
            v8s bf = __builtin_shufflevector(va, vb, 0, 1, 2, 3, 4, 5, 6, 7);
            #pragma unroll
            for (int m = 0; m < 2; ++m)
                acc[m][n] = __builtin_amdgcn_mfma_f32_16x16x32_bf16(a[m], bf, acc[m][n], 0, 0, 0);
        }
    }

    #pragma unroll
    for (int n = 0; n < 2; ++n) {
        int px = px0 + wcol*32 + n*16 + ln16;
        #pragma unroll
        for (int m = 0; m < 2; ++m)
            #pragma unroll
            for (int r = 0; r < 4; ++r) {
                int o = wrow*32 + m*16 + q*4 + r;
                out[((size_t)(b*C_ + o)*H_ + h)*W_ + px] = acc[m][n][r] + bc[o];
            }
    }
}

// ---------------------------------------------------------------------------
extern "C" void kernel_launch(void* const* d_in, const int* in_sizes, int n_in,
                              void* d_out, int out_size, void* d_ws, size_t ws_size,
                              hipStream_t stream)
{
    const float* x0  = (const float*)d_in[0];
    const float* spa = (const float*)d_in[1];
    const float* gum = (const float*)d_in[2];
    const float* par = (const float*)d_in[3];
    const float* w0  = (const float*)d_in[4];
    const float* w1  = (const float*)d_in[5];
    const float* w2  = (const float*)d_in[6];
    const float* w3  = (const float*)d_in[7];
    const float* wc  = (const float*)d_in[8];
    const float* bc  = (const float*)d_in[9];
    float* out = (float*)d_out;
    char*  ws  = (char*)d_ws;

    float*  chm = (float*)(ws + CHM_B);
    ushort* pwA = (ushort*)(ws + PWA_B);
    ushort* AH  = (ushort*)(ws + AH_B);
    ushort* fea0 = (ushort*)(ws + FEA_B(0));
    ushort* fea1 = (ushort*)(ws + FEA_B(1));
    ushort* fea2 = (ushort*)(ws + FEA_B(2));
    ushort* fea3 = (ushort*)(ws + FEA_B(3));

    mask_kernel<<<1, 64, 0, stream>>>(gum, par, chm, out + OUT_ELEMS);
    prep_kernel<<<1072, 256, 0, stream>>>(w0, w1, w2, w3, wc, chm, AH, pwA);

    conv_bf16<1, true ><<<2048, 256, 0, stream>>>(x0,   AH + A_S0,  chm, spa, fea0, 0);
    conv_bf16<2, false><<<2048, 256, 0, stream>>>(fea0, AH + A_S(1), chm, spa, fea1, 1);
    conv_bf16<2, false><<<2048, 256, 0, stream>>>(fea1, AH + A_S(2), chm, spa, fea2, 2);
    conv_bf16<2, false><<<2048, 256, 0, stream>>>(fea2, AH + A_S(3), chm, spa, fea3, 3);

    pw_final<<<4096, 256, 0, stream>>>(fea0, pwA, bc, out);
}